// Round 1
// baseline (4409.830 us; speedup 1.0000x reference)
//
#include <hip/hip_runtime.h>
#include <stdint.h>

#define B_ 128
#define T_ 512
#define H_ 256
#define K_ 512          // concat K (x|h or h1|h2)
#define NBLK 32         // blocks per layer
#define HS 8            // h-cols per block

typedef short bf16x8 __attribute__((ext_vector_type(8)));   // 8 bf16 = 4 VGPRs
typedef float f32x4 __attribute__((ext_vector_type(4)));

__device__ __forceinline__ unsigned short f2bf(float f) {
    union { float f; uint32_t u; } v; v.f = f;
    uint32_t u = v.u;
    return (unsigned short)((u + 0x7FFFu + ((u >> 16) & 1u)) >> 16);  // RNE
}
__device__ __forceinline__ float sigm(float x) { return 1.0f / (1.0f + __expf(-x)); }
__device__ __forceinline__ float tanh_(float x) { return 1.0f - 2.0f / (__expf(2.0f * x) + 1.0f); }

// ---- prep: x[b][t][f] fp32 -> xbf[t][b][f] bf16 ----
__global__ void k_prep_x(const float* __restrict__ x, unsigned short* __restrict__ xbf) {
    int idx = blockIdx.x * blockDim.x + threadIdx.x;   // over B*T*F/4
    int f4 = idx & 63;
    int t = (idx >> 6) & 511;
    int b = idx >> 15;
    float4 v = *(const float4*)(x + ((size_t)b * T_ + t) * H_ + f4 * 4);
    ushort4 o;
    o.x = f2bf(v.x); o.y = f2bf(v.y); o.z = f2bf(v.z); o.w = f2bf(v.w);
    *(ushort4*)(xbf + ((size_t)t * B_ + b) * H_ + f4 * 4) = o;
}

// ---- prep: Wt[col][k] bf16 (col<1024, k<512); k<256 from Wx, else Wh ----
__global__ void k_prep_w(const float* __restrict__ Wx, const float* __restrict__ Wh,
                         unsigned short* __restrict__ Wt) {
    int idx = blockIdx.x * blockDim.x + threadIdx.x;   // over 1024*512
    int k = idx & 511; int col = idx >> 9;
    float v = (k < 256) ? Wx[(size_t)k * 1024 + col] : Wh[(size_t)(k - 256) * 1024 + col];
    Wt[(size_t)col * 512 + k] = f2bf(v);
}

__global__ void k_prep_wd(const float* __restrict__ Wd, unsigned short* __restrict__ Wdt) {
    int idx = blockIdx.x * blockDim.x + threadIdx.x;   // 256*256
    int k = idx & 255; int col = idx >> 8;
    Wdt[(size_t)col * 256 + k] = f2bf(Wd[(size_t)k * 256 + col]);
}

// ---- persistent fused 2-layer LSTM recurrence ----
// grid = 64 blocks x 256 thr: blocks [0,32) layer1 (A=[x_t ; h1_{t-1}]),
// [32,64) layer2 (A=[h1_t ; h2_{t-1}]). Block owns HS=8 h-cols (N=32 gate cols).
__global__ __launch_bounds__(256, 1) void k_lstm(
    const unsigned short* __restrict__ xbf,
    const unsigned short* __restrict__ Wt1, const unsigned short* __restrict__ Wt2,
    const float* __restrict__ b0, const float* __restrict__ b1,
    unsigned short* __restrict__ h1buf, unsigned short* __restrict__ h2buf,
    const unsigned short* __restrict__ zslab, int* __restrict__ flags) {
    const int layer = blockIdx.x >> 5;
    const int blk = blockIdx.x & 31;
    const int hbase = blk * HS;
    const int tid = threadIdx.x;
    const int wave = tid >> 6;
    const int lane = tid & 63;
    const int quad = lane >> 4;
    const int l15 = lane & 15;
    const bool lo = (l15 < 8);

    const unsigned short* Wt = layer ? Wt2 : Wt1;
    const float* bias = layer ? b1 : b0;
    unsigned short* hout = layer ? h2buf : h1buf;
    int* fl_h1 = flags;                 // layer-1 completion counters [T]
    int* fl_own = flags + layer * T_;   // own layer's counters

    // virtual cols: nt0 = [i-strip | f-strip], nt1 = [g-strip | o-strip]
    int col[2];
#pragma unroll
    for (int nt = 0; nt < 2; ++nt) {
        int g0 = nt * 512;
        col[nt] = lo ? (g0 + hbase + l15) : (g0 + 256 + hbase + (l15 - 8));
    }
    float bia[2]; bia[0] = bias[col[0]]; bia[1] = bias[col[1]];

    // B fragments register-resident for all 512 steps (32 frags = 128 VGPRs)
    bf16x8 Bf[16][2];
#pragma unroll
    for (int kt = 0; kt < 16; ++kt)
#pragma unroll
        for (int nt = 0; nt < 2; ++nt)
            Bf[kt][nt] = *(const bf16x8*)(Wt + (size_t)col[nt] * K_ + kt * 32 + quad * 8);

    float creg[2][4];
#pragma unroll
    for (int m = 0; m < 2; ++m)
#pragma unroll
        for (int r = 0; r < 4; ++r) creg[m][r] = 0.f;

    const int rowbase = wave * 32;
    const f32x4 zero = {0.f, 0.f, 0.f, 0.f};

    for (int t = 0; t < T_; ++t) {
        if (tid == 0) {
            if (layer == 0) {
                if (t > 0)
                    while (__hip_atomic_load(fl_h1 + (t - 1), __ATOMIC_RELAXED, __HIP_MEMORY_SCOPE_AGENT) < NBLK) {}
            } else {
                while (__hip_atomic_load(fl_h1 + t, __ATOMIC_RELAXED, __HIP_MEMORY_SCOPE_AGENT) < NBLK) {}
                if (t > 0)
                    while (__hip_atomic_load(fl_own + (t - 1), __ATOMIC_RELAXED, __HIP_MEMORY_SCOPE_AGENT) < NBLK) {}
            }
            __builtin_amdgcn_fence(__ATOMIC_ACQUIRE, "agent");
        }
        __syncthreads();

        const unsigned short* A0 = layer ? (h1buf + (size_t)t * B_ * H_)
                                         : (xbf + (size_t)t * B_ * H_);
        const unsigned short* A1 = (t == 0) ? zslab
                                 : (layer ? (h2buf + (size_t)(t - 1) * B_ * H_)
                                          : (h1buf + (size_t)(t - 1) * B_ * H_));

        f32x4 acc[2][2];
#pragma unroll
        for (int m = 0; m < 2; ++m) { acc[m][0] = zero; acc[m][1] = zero; }

#pragma unroll
        for (int m = 0; m < 2; ++m) {
            int row = rowbase + m * 16 + l15;
            const unsigned short* pa0 = A0 + (size_t)row * H_ + quad * 8;
            const unsigned short* pa1 = A1 + (size_t)row * H_ + quad * 8;
#pragma unroll
            for (int kt = 0; kt < 8; ++kt) {
                bf16x8 a = *(const bf16x8*)(pa0 + kt * 32);
                acc[m][0] = __builtin_amdgcn_mfma_f32_16x16x32_bf16(a, Bf[kt][0], acc[m][0], 0, 0, 0);
                acc[m][1] = __builtin_amdgcn_mfma_f32_16x16x32_bf16(a, Bf[kt][1], acc[m][1], 0, 0, 0);
            }
#pragma unroll
            for (int kt = 0; kt < 8; ++kt) {
                bf16x8 a = *(const bf16x8*)(pa1 + kt * 32);
                acc[m][0] = __builtin_amdgcn_mfma_f32_16x16x32_bf16(a, Bf[8 + kt][0], acc[m][0], 0, 0, 0);
                acc[m][1] = __builtin_amdgcn_mfma_f32_16x16x32_bf16(a, Bf[8 + kt][1], acc[m][1], 0, 0, 0);
            }
        }

        unsigned short* hdst = hout + (size_t)t * B_ * H_;
#pragma unroll
        for (int m = 0; m < 2; ++m) {
#pragma unroll
            for (int r = 0; r < 4; ++r) {
                float a0 = acc[m][0][r] + bia[0];   // i (lo) / f (hi)
                float a1 = acc[m][1][r] + bia[1];   // g (lo) / o (hi)
                float p0 = __shfl_xor(a0, 8);
                float p1 = __shfl_xor(a1, 8);
                float zi = lo ? a0 : p0;
                float zf = lo ? p0 : a0;
                float zg = lo ? a1 : p1;
                float zo = lo ? p1 : a1;
                float gi = sigm(zi), gf = sigm(zf), gg = tanh_(zg), go = sigm(zo);
                float c = gf * creg[m][r] + gi * gg;
                creg[m][r] = c;
                float h = go * tanh_(c);
                if (lo) {
                    int row = rowbase + m * 16 + quad * 4 + r;
                    hdst[(size_t)row * H_ + hbase + l15] = f2bf(h);
                }
            }
        }
        __syncthreads();
        if (tid == 0) {
            __builtin_amdgcn_fence(__ATOMIC_RELEASE, "agent");
            __hip_atomic_fetch_add(fl_own + t, 1, __ATOMIC_RELAXED, __HIP_MEMORY_SCOPE_AGENT);
        }
    }
}

// ---- Dense(tanh) + LayerNorm, one block per t (128 rows), full N=256 in regs ----
__global__ __launch_bounds__(256, 2) void k_dense_ln(
    const unsigned short* __restrict__ h2buf, const unsigned short* __restrict__ Wdt,
    const float* __restrict__ bd, const float* __restrict__ gamma,
    const float* __restrict__ beta, float* __restrict__ out) {
    const int t = blockIdx.x;
    const int tid = threadIdx.x;
    const int wave = tid >> 6, lane = tid & 63, quad = lane >> 4, l15 = lane & 15;
    const unsigned short* A = h2buf + (size_t)t * B_ * H_;
    const f32x4 zero = {0.f, 0.f, 0.f, 0.f};

    f32x4 acc[2][16];
#pragma unroll
    for (int m = 0; m < 2; ++m)
#pragma unroll
        for (int n = 0; n < 16; ++n) acc[m][n] = zero;

#pragma unroll
    for (int kt = 0; kt < 8; ++kt) {
        bf16x8 a[2];
#pragma unroll
        for (int m = 0; m < 2; ++m) {
            int row = wave * 32 + m * 16 + l15;
            a[m] = *(const bf16x8*)(A + (size_t)row * H_ + kt * 32 + quad * 8);
        }
#pragma unroll
        for (int n = 0; n < 16; ++n) {
            bf16x8 b = *(const bf16x8*)(Wdt + (size_t)(n * 16 + l15) * H_ + kt * 32 + quad * 8);
            acc[0][n] = __builtin_amdgcn_mfma_f32_16x16x32_bf16(a[0], b, acc[0][n], 0, 0, 0);
            acc[1][n] = __builtin_amdgcn_mfma_f32_16x16x32_bf16(a[1], b, acc[1][n], 0, 0, 0);
        }
    }

    float gm[16], bt[16], bdv[16];
#pragma unroll
    for (int n = 0; n < 16; ++n) {
        int c = n * 16 + l15;
        gm[n] = gamma[c]; bt[n] = beta[c]; bdv[n] = bd[c];
    }
#pragma unroll
    for (int m = 0; m < 2; ++m) {
#pragma unroll
        for (int r = 0; r < 4; ++r) {
            float v[16], s = 0.f, sq = 0.f;
#pragma unroll
            for (int n = 0; n < 16; ++n) {
                float x = tanh_(acc[m][n][r] + bdv[n]);
                v[n] = x; s += x; sq += x * x;
            }
#pragma unroll
            for (int off = 1; off < 16; off <<= 1) {
                s += __shfl_xor(s, off);
                sq += __shfl_xor(sq, off);
            }
            float mu = s * (1.f / 256.f);
            float var = sq * (1.f / 256.f) - mu * mu;
            float rs = rsqrtf(var + 1e-3f);
            int row = wave * 32 + m * 16 + quad * 4 + r;   // batch index
            float* po = out + (size_t)row * (T_ * H_) + (size_t)t * H_;
#pragma unroll
            for (int n = 0; n < 16; ++n)
                po[n * 16 + l15] = (v[n] - mu) * rs * gm[n] + bt[n];
        }
    }
}

extern "C" void kernel_launch(void* const* d_in, const int* in_sizes, int n_in,
                              void* d_out, int out_size, void* d_ws, size_t ws_size,
                              hipStream_t stream) {
    const float* x     = (const float*)d_in[0];
    const float* W0    = (const float*)d_in[1];
    const float* U0    = (const float*)d_in[2];
    const float* b0    = (const float*)d_in[3];
    const float* W1    = (const float*)d_in[4];
    const float* U1    = (const float*)d_in[5];
    const float* b1    = (const float*)d_in[6];
    const float* Wd    = (const float*)d_in[7];
    const float* bd    = (const float*)d_in[8];
    const float* gamma = (const float*)d_in[9];
    const float* beta  = (const float*)d_in[10];
    float* out = (float*)d_out;

    char* ws = (char*)d_ws;
    unsigned short* xbf = (unsigned short*)(ws);               // 32 MB  [T][B][F] bf16
    unsigned short* h1b = (unsigned short*)(ws + 33554432);    // 32 MB  [T][B][H] bf16
    unsigned short* h2b = (unsigned short*)(ws + 67108864);    // 32 MB  [T][B][H] bf16
    unsigned short* Wt1 = (unsigned short*)(ws + 100663296);   // 1 MB   [1024][512] bf16
    unsigned short* Wt2 = (unsigned short*)(ws + 101711872);   // 1 MB
    unsigned short* Wdt = (unsigned short*)(ws + 102760448);   // 128 KB [256][256] bf16
    unsigned short* zsl = (unsigned short*)(ws + 102891520);   // 64 KB zero slab
    int* flags          = (int*)(ws + 102957056);              // 4 KB   [2][T]

    hipMemsetAsync(zsl, 0, 65536 + 4096, stream);              // zero slab + flags
    k_prep_x<<<16384, 256, 0, stream>>>(x, xbf);
    k_prep_w<<<2048, 256, 0, stream>>>(W0, U0, Wt1);
    k_prep_w<<<2048, 256, 0, stream>>>(W1, U1, Wt2);
    k_prep_wd<<<256, 256, 0, stream>>>(Wd, Wdt);
    k_lstm<<<64, 256, 0, stream>>>(xbf, Wt1, Wt2, b0, b1, h1b, h2b, zsl, flags);
    k_dense_ln<<<512, 256, 0, stream>>>(h2b, Wdt, bd, gamma, beta, out);
}